// Round 9
// baseline (49.219 us; speedup 1.0000x reference)
//
#include <hip/hip_runtime.h>
#include <cstdint>

// Problem constants (match reference)
#define BB 32
#define NN 32768
#define CC 21
#define K1_BLK 256
#define PPT 2                                  // priors per thread
#define TILE (K1_BLK * PPT)                    // 512
#define K1_GRID ((BB * NN) / TILE)             // 2048
#define BLKROW (NN / TILE)                     // 64 k1-blocks per row

// K2 geometry
#define K2T 1024
#define NC 16                                  // level-1 hist copies

typedef float f4 __attribute__((ext_vector_type(4)));

// native transcendentals (1-ulp; output threshold 0.39 absolute -> huge slack)
__device__ __forceinline__ float fexp2(float x) {
    float r; asm("v_exp_f32 %0, %1" : "=v"(r) : "v"(x)); return r;
}
__device__ __forceinline__ float flog2(float x) {
    float r; asm("v_log_f32 %0, %1" : "=v"(r) : "v"(x)); return r;
}

// ---------------------------------------------------------------------------
// K1 v5 (R6-best, unchanged except done-reset): register streaming,
// 2 priors/thread, all loads batched up-front for MLP.
// ---------------------------------------------------------------------------
__global__ __launch_bounds__(K1_BLK) void k1_compute(
    const float* __restrict__ conf, const float* __restrict__ pred,
    const int* __restrict__ labels, const float* __restrict__ gt,
    unsigned* __restrict__ keys, float* __restrict__ pce,
    float* __restrict__ psl1, int* __restrict__ pcnt,
    unsigned* __restrict__ done)
{
    __shared__ float wce[4], wsl[4];
    __shared__ int   wcnt[4];

    const int tid = threadIdx.x;
    const int lane = tid & 63;
    const int wid = tid >> 6;
    const size_t p0 = (size_t)blockIdx.x * TILE + tid;
    const size_t p1 = p0 + K1_BLK;

    if (blockIdx.x == 0 && tid == 0) *done = 0u;   // k2's counter starts clean

    // ---- issue ALL loads up front, nothing consumed yet
    const int lab0 = labels[p0];
    const int lab1 = labels[p1];
    const float* cp0 = conf + p0 * CC;
    const float* cp1 = conf + p1 * CC;
    f4 A0, A1, A2, A3, A4, B0, B1, B2, B3, B4;
    __builtin_memcpy(&A0, cp0 +  0, 16);
    __builtin_memcpy(&A1, cp0 +  4, 16);
    __builtin_memcpy(&A2, cp0 +  8, 16);
    __builtin_memcpy(&A3, cp0 + 12, 16);
    __builtin_memcpy(&A4, cp0 + 16, 16);
    __builtin_memcpy(&B0, cp1 +  0, 16);
    __builtin_memcpy(&B1, cp1 +  4, 16);
    __builtin_memcpy(&B2, cp1 +  8, 16);
    __builtin_memcpy(&B3, cp1 + 12, 16);
    __builtin_memcpy(&B4, cp1 + 16, 16);
    const float a20 = cp0[20];
    const float b20 = cp1[20];

    const bool pos0 = lab0 > 0;
    const bool pos1 = lab1 > 0;

    // sparse (~3%) SmoothL1 for both priors
    float sl = 0.f;
    if (pos0) {
        const float* pp = pred + p0 * 5;
        const float* gg = gt + p0 * 5;
#pragma unroll
        for (int j = 0; j < 5; ++j) {
            float d = fabsf(pp[j] - gg[j]);
            sl += (d < 1.f) ? 0.5f * d * d : (d - 0.5f);
        }
    }
    if (pos1) {
        const float* pp = pred + p1 * 5;
        const float* gg = gt + p1 * 5;
#pragma unroll
        for (int j = 0; j < 5; ++j) {
            float d = fabsf(pp[j] - gg[j]);
            sl += (d < 1.f) ? 0.5f * d * d : (d - 0.5f);
        }
    }

    // ---- prior 0: 21-class lse + logp[lab] gather via selects
    float s0 = 0.f, cl0 = 0.f;
#define KS(Q, J, IDX, LAB, SACC, CACC) { const float v_ = Q[J]; \
        SACC += fexp2(v_ * 1.44269504f); \
        CACC = ((IDX) == (LAB)) ? v_ : CACC; }
    KS(A0,0,0,lab0,s0,cl0) KS(A0,1,1,lab0,s0,cl0) KS(A0,2,2,lab0,s0,cl0) KS(A0,3,3,lab0,s0,cl0)
    KS(A1,0,4,lab0,s0,cl0) KS(A1,1,5,lab0,s0,cl0) KS(A1,2,6,lab0,s0,cl0) KS(A1,3,7,lab0,s0,cl0)
    KS(A2,0,8,lab0,s0,cl0) KS(A2,1,9,lab0,s0,cl0) KS(A2,2,10,lab0,s0,cl0) KS(A2,3,11,lab0,s0,cl0)
    KS(A3,0,12,lab0,s0,cl0) KS(A3,1,13,lab0,s0,cl0) KS(A3,2,14,lab0,s0,cl0) KS(A3,3,15,lab0,s0,cl0)
    KS(A4,0,16,lab0,s0,cl0) KS(A4,1,17,lab0,s0,cl0) KS(A4,2,18,lab0,s0,cl0) KS(A4,3,19,lab0,s0,cl0)
    { const float v_ = a20; s0 += fexp2(v_ * 1.44269504f); cl0 = (20 == lab0) ? v_ : cl0; }
    const float lse0 = 0.6931471805599453f * flog2(s0);
    const float mining0 = fmaxf(lse0 - A0[0], 0.f);
    keys[p0] = pos0 ? 0u : __float_as_uint(mining0);
    float ce = pos0 ? (lse0 - cl0) : 0.f;
    int cnt = pos0 ? 1 : 0;

    // ---- prior 1
    float s1 = 0.f, cl1 = 0.f;
    KS(B0,0,0,lab1,s1,cl1) KS(B0,1,1,lab1,s1,cl1) KS(B0,2,2,lab1,s1,cl1) KS(B0,3,3,lab1,s1,cl1)
    KS(B1,0,4,lab1,s1,cl1) KS(B1,1,5,lab1,s1,cl1) KS(B1,2,6,lab1,s1,cl1) KS(B1,3,7,lab1,s1,cl1)
    KS(B2,0,8,lab1,s1,cl1) KS(B2,1,9,lab1,s1,cl1) KS(B2,2,10,lab1,s1,cl1) KS(B2,3,11,lab1,s1,cl1)
    KS(B3,0,12,lab1,s1,cl1) KS(B3,1,13,lab1,s1,cl1) KS(B3,2,14,lab1,s1,cl1) KS(B3,3,15,lab1,s1,cl1)
    KS(B4,0,16,lab1,s1,cl1) KS(B4,1,17,lab1,s1,cl1) KS(B4,2,18,lab1,s1,cl1) KS(B4,3,19,lab1,s1,cl1)
    { const float v_ = b20; s1 += fexp2(v_ * 1.44269504f); cl1 = (20 == lab1) ? v_ : cl1; }
#undef KS
    const float lse1 = 0.6931471805599453f * flog2(s1);
    const float mining1 = fmaxf(lse1 - B0[0], 0.f);
    keys[p1] = pos1 ? 0u : __float_as_uint(mining1);
    ce += pos1 ? (lse1 - cl1) : 0.f;
    cnt += pos1 ? 1 : 0;

    // ---- deterministic block reduction (fixed trees)
#pragma unroll
    for (int d = 32; d > 0; d >>= 1) {
        ce  += __shfl_down(ce, d);
        sl  += __shfl_down(sl, d);
        cnt += __shfl_down(cnt, d);
    }
    if (lane == 0) { wce[wid] = ce; wsl[wid] = sl; wcnt[wid] = cnt; }
    __syncthreads();
    if (tid == 0) {
        float tce = 0.f, tsl = 0.f; int tc = 0;
#pragma unroll
        for (int w = 0; w < 4; ++w) { tce += wce[w]; tsl += wsl[w]; tc += wcnt[w]; }
        pce[blockIdx.x]  = tce;
        psl1[blockIdx.x] = tsl;
        pcnt[blockIdx.x] = tc;     // non-atomic per-block count
    }
}

// ---------------------------------------------------------------------------
// Suffix-scan over 2048 bins (2 bins/thread) + crossing pick.
// ---------------------------------------------------------------------------
template <class GET>
__device__ __forceinline__ void sscan2048(
    GET get, unsigned* ss, unsigned* swsum,
    int* s_bin, int* s_above, unsigned want, int tid, int lane, int wid)
{
    const int b0 = 2047 - 2 * tid;     // descending scan order
    const int b1 = 2046 - 2 * tid;
    const unsigned m0 = get(b0), m1 = get(b1);
    unsigned v = m0 + m1;
#pragma unroll
    for (int d = 1; d < 64; d <<= 1) {
        unsigned u = __shfl_up(v, d);
        if (lane >= d) v += u;
    }
    if (lane == 63) swsum[wid] = v;
    __syncthreads();
    if (wid == 0) {
        unsigned wv = (lane < 16) ? swsum[lane] : 0;
#pragma unroll
        for (int d = 1; d < 16; d <<= 1) {
            unsigned u = __shfl_up(wv, d);
            if (lane >= d) wv += u;
        }
        if (lane < 16) swsum[lane] = wv;
    }
    __syncthreads();
    const unsigned off = wid ? swsum[wid - 1] : 0;
    const unsigned incl = off + v;     // suffix through b1
    const unsigned sb0 = incl - m1;    // suffix through b0
    ss[b0] = sb0;
    ss[b1] = incl;
    __syncthreads();
    if (sb0 >= want && (b0 == 2047 || ss[b0 + 1] < want)) {
        *s_bin = b0; *s_above = (b0 == 2047) ? 0 : (int)ss[b0 + 1];
    }
    if (incl >= want && ss[b1 + 1] < want) {
        *s_bin = b1; *s_above = (int)ss[b1 + 1];
    }
    __syncthreads();
}

// ---------------------------------------------------------------------------
// K2 v6 + k3 fold: fully register-resident exact top-k sum
// (sum = Σ(key>T) + r·T), then last-finishing block performs the global
// fixed-tree reduction and writes the two output scalars.
// ---------------------------------------------------------------------------
__global__ __launch_bounds__(K2T) void k2_select(
    const unsigned* __restrict__ keys, const int* __restrict__ pcnt,
    const float* __restrict__ pce, const float* __restrict__ psl1,
    double* __restrict__ row_sumneg, unsigned* __restrict__ done,
    float* __restrict__ out)
{
    const int b = blockIdx.x;
    const int tid = threadIdx.x;
    const int lane = tid & 63;
    const int wid = tid >> 6;
    const unsigned* rk = keys + (size_t)b * NN;

    __shared__ unsigned h1[1024 * NC];  // 64 KB (reused for levels 2/3)
    __shared__ unsigned ss[2048];       // 8 KB suffix sums
    __shared__ unsigned swsum[16];
    __shared__ double sdred[16];
    __shared__ double fA[16], fB[16];
    __shared__ int fI[16];
    __shared__ int s_bin, s_above, s_last;
    __shared__ unsigned s_want;

    // ---- one coalesced read: 8 x uint4 per thread -> 32 keys in VGPRs
    uint4 kv[8];
    const uint4* rk4 = reinterpret_cast<const uint4*>(rk);
#pragma unroll
    for (int j = 0; j < 8; ++j) kv[j] = rk4[tid + j * K2T];

    // want = min(3 * row positives, NN)
    if (wid == 0) {
        int c = pcnt[b * BLKROW + lane];          // BLKROW == 64 == wave
#pragma unroll
        for (int d = 32; d > 0; d >>= 1) c += __shfl_down(c, d);
        if (lane == 0) s_want = (unsigned)((3 * c > NN) ? NN : 3 * c);
    }
    for (int i = tid; i < 1024 * NC; i += K2T) h1[i] = 0;
    __syncthreads();
    const unsigned want = s_want;

    if (want > 0) {
        // ---- level 1: 1024-bin hist of bits[31:21] (finite >=0 -> <=1019)
        const unsigned cp = lane & (NC - 1);
#pragma unroll
        for (int j = 0; j < 8; ++j) {
            atomicAdd(&h1[((kv[j].x >> 21) << 4) | cp], 1u);
            atomicAdd(&h1[((kv[j].y >> 21) << 4) | cp], 1u);
            atomicAdd(&h1[((kv[j].z >> 21) << 4) | cp], 1u);
            atomicAdd(&h1[((kv[j].w >> 21) << 4) | cp], 1u);
        }
        __syncthreads();

        // ---- level-1 scan: one bin/thread, descending suffix sums
        {
            const int bn = 1023 - tid;
            unsigned mv = 0;
#pragma unroll
            for (int c = 0; c < NC; ++c) mv += h1[(bn << 4) | c];
            unsigned v = mv;
#pragma unroll
            for (int d = 1; d < 64; d <<= 1) {
                unsigned u = __shfl_up(v, d);
                if (lane >= d) v += u;
            }
            if (lane == 63) swsum[wid] = v;
            __syncthreads();
            if (wid == 0) {
                unsigned wv = (lane < 16) ? swsum[lane] : 0;
#pragma unroll
                for (int d = 1; d < 16; d <<= 1) {
                    unsigned u = __shfl_up(wv, d);
                    if (lane >= d) wv += u;
                }
                if (lane < 16) swsum[lane] = wv;
            }
            __syncthreads();
            const unsigned incl = (wid ? swsum[wid - 1] : 0) + v;
            ss[bn] = incl;
            __syncthreads();
            if (incl >= want && (bn == 1023 || ss[bn + 1] < want)) {
                s_bin = bn; s_above = (bn == 1023) ? 0 : (int)ss[bn + 1];
            }
            __syncthreads();
        }
        const unsigned bsel1 = (unsigned)s_bin;
        const unsigned want1 = want - (unsigned)s_above;

        // ---- level 2: bits[20:10] of in-bin keys, straight from registers
        for (int i = tid; i < 4096; i += K2T) h1[i] = 0;
        __syncthreads();
        const unsigned c2 = lane & 1;
#pragma unroll
        for (int j = 0; j < 8; ++j) {
#define L2ADD(K) if (((K) >> 21) == bsel1) \
            atomicAdd(&h1[((((K) >> 10) & 0x7FFu) << 1) | c2], 1u);
            L2ADD(kv[j].x) L2ADD(kv[j].y) L2ADD(kv[j].z) L2ADD(kv[j].w)
#undef L2ADD
        }
        __syncthreads();
        sscan2048([&](int bn) { return h1[bn << 1] + h1[(bn << 1) | 1]; },
                  ss, swsum, &s_bin, &s_above, want1, tid, lane, wid);
        const unsigned bsel2 = (unsigned)s_bin;
        const unsigned want2 = want1 - (unsigned)s_above;

        // ---- level 3: bits[9:0] (1024 live bins; upper 1024 stay zero)
        for (int i = tid; i < 4096; i += K2T) h1[i] = 0;
        __syncthreads();
        const unsigned pref = (bsel1 << 11) | bsel2;   // key bits[31:10]
#pragma unroll
        for (int j = 0; j < 8; ++j) {
#define L3ADD(K) if (((K) >> 10) == pref) \
            atomicAdd(&h1[(((K) & 0x3FFu) << 1) | c2], 1u);
            L3ADD(kv[j].x) L3ADD(kv[j].y) L3ADD(kv[j].z) L3ADD(kv[j].w)
#undef L3ADD
        }
        __syncthreads();
        sscan2048([&](int bn) { return h1[bn << 1] + h1[(bn << 1) | 1]; },
                  ss, swsum, &s_bin, &s_above, want2, tid, lane, wid);
        const unsigned T = (bsel1 << 21) | (bsel2 << 10) | (unsigned)s_bin;

        // ---- final: one register pass over all 32 keys
        int above = 0;
        double sel = 0.0;
#pragma unroll
        for (int j = 0; j < 8; ++j) {
#define FIN(K) if ((K) > T) { above++; sel += (double)__uint_as_float(K); }
            FIN(kv[j].x) FIN(kv[j].y) FIN(kv[j].z) FIN(kv[j].w)
#undef FIN
        }
#pragma unroll
        for (int d = 32; d > 0; d >>= 1) {
            above += __shfl_down(above, d);
            sel   += __shfl_down(sel, d);
        }
        if (lane == 0) { swsum[wid] = (unsigned)above; sdred[wid] = sel; }
        __syncthreads();
        if (tid == 0) {
            unsigned atot = 0; double stot = 0.0;
#pragma unroll
            for (int w = 0; w < 16; ++w) { atot += swsum[w]; stot += sdred[w]; }
            const int r = (int)want - (int)atot;   // # of ==T entries selected
            row_sumneg[b] = stot + (double)r * (double)__uint_as_float(T);
        }
    } else {
        if (tid == 0) row_sumneg[b] = 0.0;
    }

    // ---- completion: last block does the (deterministic) global reduction
    __threadfence();
    if (tid == 0) s_last = (atomicAdd(done, 1u) == BB - 1) ? 1 : 0;
    __syncthreads();
    if (s_last) {
        __threadfence();   // acquire: see all blocks' row_sumneg
        double ce = 0.0, sl = 0.0; int np = 0;
        for (int i = tid; i < K1_GRID; i += K2T) {   // 2 iterations
            ce += (double)pce[i];
            sl += (double)psl1[i];
            np += pcnt[i];
        }
#pragma unroll
        for (int d = 32; d > 0; d >>= 1) {
            ce += __shfl_down(ce, d);
            sl += __shfl_down(sl, d);
            np += __shfl_down(np, d);
        }
        if (lane == 0) { fA[wid] = ce; fB[wid] = sl; fI[wid] = np; }
        __syncthreads();
        if (tid == 0) {
            double tce = 0.0, tsl = 0.0; int tnp = 0;
#pragma unroll
            for (int w = 0; w < 16; ++w) { tce += fA[w]; tsl += fB[w]; tnp += fI[w]; }
            double ns = 0.0;
            for (int bb = 0; bb < BB; ++bb) ns += row_sumneg[bb];
            const double npos = (double)tnp;
            out[0] = (float)(tsl / npos);          // smooth_l1_loss / n_pos
            out[1] = (float)((tce + ns) / npos);   // classification_loss / n_pos
        }
    }
}

// ---------------------------------------------------------------------------
extern "C" void kernel_launch(void* const* d_in, const int* in_sizes, int n_in,
                              void* d_out, int out_size, void* d_ws, size_t ws_size,
                              hipStream_t stream)
{
    const float* conf   = (const float*)d_in[0];
    const float* pred   = (const float*)d_in[1];
    const int*   labels = (const int*)d_in[2];
    const float* gt     = (const float*)d_in[3];
    float* out = (float*)d_out;

    char* ws = (char*)d_ws;
    unsigned* keys       = (unsigned*)ws;                      // 4 MB
    float*    pce        = (float*)(ws + 4194304);             // 8 KB
    float*    psl1       = (float*)(ws + 4202496);             // 8 KB
    int*      pcnt       = (int*)(ws + 4210688);               // 8 KB
    double*   row_sumneg = (double*)(ws + 4218880);            // 256 B
    unsigned* done       = (unsigned*)(ws + 4219136);          // 4 B

    k1_compute<<<K1_GRID, K1_BLK, 0, stream>>>(conf, pred, labels, gt,
                                               keys, pce, psl1, pcnt, done);
    k2_select<<<BB, K2T, 0, stream>>>(keys, pcnt, pce, psl1,
                                      row_sumneg, done, out);
}

// Round 10
// 39.781 us; speedup vs baseline: 1.2373x; 1.2373x over previous
//
#include <hip/hip_runtime.h>
#include <cstdint>

// Problem constants (match reference)
#define BB 32
#define NN 32768
#define CC 21
#define K1_BLK 256
#define PPT 2                                  // priors per thread
#define TILE (K1_BLK * PPT)                    // 512
#define K1_GRID ((BB * NN) / TILE)             // 2048
#define BLKROW (NN / TILE)                     // 64 k1-blocks per row

// K2 geometry
#define K2T 1024
#define NC 16                                  // level-1 hist copies

typedef float f4 __attribute__((ext_vector_type(4)));

// native transcendentals (1-ulp; output threshold 0.39 absolute -> huge slack)
__device__ __forceinline__ float fexp2(float x) {
    float r; asm("v_exp_f32 %0, %1" : "=v"(r) : "v"(x)); return r;
}
__device__ __forceinline__ float flog2(float x) {
    float r; asm("v_log_f32 %0, %1" : "=v"(r) : "v"(x)); return r;
}

// ---------------------------------------------------------------------------
// K1 v5 (R6-best, byte-identical): register streaming, 2 priors/thread,
// all loads batched up-front for memory-level parallelism.
// ---------------------------------------------------------------------------
__global__ __launch_bounds__(K1_BLK) void k1_compute(
    const float* __restrict__ conf, const float* __restrict__ pred,
    const int* __restrict__ labels, const float* __restrict__ gt,
    unsigned* __restrict__ keys, float* __restrict__ pce,
    float* __restrict__ psl1, int* __restrict__ pcnt)
{
    __shared__ float wce[4], wsl[4];
    __shared__ int   wcnt[4];

    const int tid = threadIdx.x;
    const int lane = tid & 63;
    const int wid = tid >> 6;
    const size_t p0 = (size_t)blockIdx.x * TILE + tid;
    const size_t p1 = p0 + K1_BLK;

    // ---- issue ALL loads up front, nothing consumed yet
    const int lab0 = labels[p0];
    const int lab1 = labels[p1];
    const float* cp0 = conf + p0 * CC;
    const float* cp1 = conf + p1 * CC;
    f4 A0, A1, A2, A3, A4, B0, B1, B2, B3, B4;
    __builtin_memcpy(&A0, cp0 +  0, 16);
    __builtin_memcpy(&A1, cp0 +  4, 16);
    __builtin_memcpy(&A2, cp0 +  8, 16);
    __builtin_memcpy(&A3, cp0 + 12, 16);
    __builtin_memcpy(&A4, cp0 + 16, 16);
    __builtin_memcpy(&B0, cp1 +  0, 16);
    __builtin_memcpy(&B1, cp1 +  4, 16);
    __builtin_memcpy(&B2, cp1 +  8, 16);
    __builtin_memcpy(&B3, cp1 + 12, 16);
    __builtin_memcpy(&B4, cp1 + 16, 16);
    const float a20 = cp0[20];
    const float b20 = cp1[20];

    const bool pos0 = lab0 > 0;
    const bool pos1 = lab1 > 0;

    // sparse (~3%) SmoothL1 for both priors
    float sl = 0.f;
    if (pos0) {
        const float* pp = pred + p0 * 5;
        const float* gg = gt + p0 * 5;
#pragma unroll
        for (int j = 0; j < 5; ++j) {
            float d = fabsf(pp[j] - gg[j]);
            sl += (d < 1.f) ? 0.5f * d * d : (d - 0.5f);
        }
    }
    if (pos1) {
        const float* pp = pred + p1 * 5;
        const float* gg = gt + p1 * 5;
#pragma unroll
        for (int j = 0; j < 5; ++j) {
            float d = fabsf(pp[j] - gg[j]);
            sl += (d < 1.f) ? 0.5f * d * d : (d - 0.5f);
        }
    }

    // ---- prior 0: 21-class lse + logp[lab] gather via selects
    float s0 = 0.f, cl0 = 0.f;
#define KS(Q, J, IDX, LAB, SACC, CACC) { const float v_ = Q[J]; \
        SACC += fexp2(v_ * 1.44269504f); \
        CACC = ((IDX) == (LAB)) ? v_ : CACC; }
    KS(A0,0,0,lab0,s0,cl0) KS(A0,1,1,lab0,s0,cl0) KS(A0,2,2,lab0,s0,cl0) KS(A0,3,3,lab0,s0,cl0)
    KS(A1,0,4,lab0,s0,cl0) KS(A1,1,5,lab0,s0,cl0) KS(A1,2,6,lab0,s0,cl0) KS(A1,3,7,lab0,s0,cl0)
    KS(A2,0,8,lab0,s0,cl0) KS(A2,1,9,lab0,s0,cl0) KS(A2,2,10,lab0,s0,cl0) KS(A2,3,11,lab0,s0,cl0)
    KS(A3,0,12,lab0,s0,cl0) KS(A3,1,13,lab0,s0,cl0) KS(A3,2,14,lab0,s0,cl0) KS(A3,3,15,lab0,s0,cl0)
    KS(A4,0,16,lab0,s0,cl0) KS(A4,1,17,lab0,s0,cl0) KS(A4,2,18,lab0,s0,cl0) KS(A4,3,19,lab0,s0,cl0)
    { const float v_ = a20; s0 += fexp2(v_ * 1.44269504f); cl0 = (20 == lab0) ? v_ : cl0; }
    const float lse0 = 0.6931471805599453f * flog2(s0);
    const float mining0 = fmaxf(lse0 - A0[0], 0.f);
    keys[p0] = pos0 ? 0u : __float_as_uint(mining0);
    float ce = pos0 ? (lse0 - cl0) : 0.f;
    int cnt = pos0 ? 1 : 0;

    // ---- prior 1
    float s1 = 0.f, cl1 = 0.f;
    KS(B0,0,0,lab1,s1,cl1) KS(B0,1,1,lab1,s1,cl1) KS(B0,2,2,lab1,s1,cl1) KS(B0,3,3,lab1,s1,cl1)
    KS(B1,0,4,lab1,s1,cl1) KS(B1,1,5,lab1,s1,cl1) KS(B1,2,6,lab1,s1,cl1) KS(B1,3,7,lab1,s1,cl1)
    KS(B2,0,8,lab1,s1,cl1) KS(B2,1,9,lab1,s1,cl1) KS(B2,2,10,lab1,s1,cl1) KS(B2,3,11,lab1,s1,cl1)
    KS(B3,0,12,lab1,s1,cl1) KS(B3,1,13,lab1,s1,cl1) KS(B3,2,14,lab1,s1,cl1) KS(B3,3,15,lab1,s1,cl1)
    KS(B4,0,16,lab1,s1,cl1) KS(B4,1,17,lab1,s1,cl1) KS(B4,2,18,lab1,s1,cl1) KS(B4,3,19,lab1,s1,cl1)
    { const float v_ = b20; s1 += fexp2(v_ * 1.44269504f); cl1 = (20 == lab1) ? v_ : cl1; }
#undef KS
    const float lse1 = 0.6931471805599453f * flog2(s1);
    const float mining1 = fmaxf(lse1 - B0[0], 0.f);
    keys[p1] = pos1 ? 0u : __float_as_uint(mining1);
    ce += pos1 ? (lse1 - cl1) : 0.f;
    cnt += pos1 ? 1 : 0;

    // ---- deterministic block reduction (fixed trees)
#pragma unroll
    for (int d = 32; d > 0; d >>= 1) {
        ce  += __shfl_down(ce, d);
        sl  += __shfl_down(sl, d);
        cnt += __shfl_down(cnt, d);
    }
    if (lane == 0) { wce[wid] = ce; wsl[wid] = sl; wcnt[wid] = cnt; }
    __syncthreads();
    if (tid == 0) {
        float tce = 0.f, tsl = 0.f; int tc = 0;
#pragma unroll
        for (int w = 0; w < 4; ++w) { tce += wce[w]; tsl += wsl[w]; tc += wcnt[w]; }
        pce[blockIdx.x]  = tce;
        psl1[blockIdx.x] = tsl;
        pcnt[blockIdx.x] = tc;     // non-atomic per-block count
    }
}

// ---------------------------------------------------------------------------
// Suffix-scan over 2048 bins (2 bins/thread) + crossing pick.
// ---------------------------------------------------------------------------
template <class GET>
__device__ __forceinline__ void sscan2048(
    GET get, unsigned* ss, unsigned* swsum,
    int* s_bin, int* s_above, unsigned want, int tid, int lane, int wid)
{
    const int b0 = 2047 - 2 * tid;     // descending scan order
    const int b1 = 2046 - 2 * tid;
    const unsigned m0 = get(b0), m1 = get(b1);
    unsigned v = m0 + m1;
#pragma unroll
    for (int d = 1; d < 64; d <<= 1) {
        unsigned u = __shfl_up(v, d);
        if (lane >= d) v += u;
    }
    if (lane == 63) swsum[wid] = v;
    __syncthreads();
    if (wid == 0) {
        unsigned wv = (lane < 16) ? swsum[lane] : 0;
#pragma unroll
        for (int d = 1; d < 16; d <<= 1) {
            unsigned u = __shfl_up(wv, d);
            if (lane >= d) wv += u;
        }
        if (lane < 16) swsum[lane] = wv;
    }
    __syncthreads();
    const unsigned off = wid ? swsum[wid - 1] : 0;
    const unsigned incl = off + v;     // suffix through b1
    const unsigned sb0 = incl - m1;    // suffix through b0
    ss[b0] = sb0;
    ss[b1] = incl;
    __syncthreads();
    if (sb0 >= want && (b0 == 2047 || ss[b0 + 1] < want)) {
        *s_bin = b0; *s_above = (b0 == 2047) ? 0 : (int)ss[b0 + 1];
    }
    if (incl >= want && ss[b1 + 1] < want) {
        *s_bin = b1; *s_above = (int)ss[b1 + 1];
    }
    __syncthreads();
}

// ---------------------------------------------------------------------------
// K2 v6 (R6-best) + ONE change: __launch_bounds__(1024, 8) pins the
// allocator to <=64 VGPR so 2 blocks/CU co-reside (LDS 72 KB also allows
// exactly 2). Theory: v6 sat just over the 64-VGPR cliff at 1 block/CU;
// this halves exposed barrier/latency cost.
// ---------------------------------------------------------------------------
__global__ __launch_bounds__(K2T, 8) void k2_select(
    const unsigned* __restrict__ keys, const int* __restrict__ pcnt,
    double* __restrict__ row_sumneg)
{
    const int b = blockIdx.x;
    const int tid = threadIdx.x;
    const int lane = tid & 63;
    const int wid = tid >> 6;
    const unsigned* rk = keys + (size_t)b * NN;

    __shared__ unsigned h1[1024 * NC];  // 64 KB (reused for levels 2/3)
    __shared__ unsigned ss[2048];       // 8 KB suffix sums
    __shared__ unsigned swsum[16];
    __shared__ double sdred[16];
    __shared__ int s_bin, s_above;
    __shared__ unsigned s_want;

    // ---- one coalesced read: 8 x uint4 per thread -> 32 keys in VGPRs
    uint4 kv[8];
    const uint4* rk4 = reinterpret_cast<const uint4*>(rk);
#pragma unroll
    for (int j = 0; j < 8; ++j) kv[j] = rk4[tid + j * K2T];

    // want = min(3 * row positives, NN)
    if (wid == 0) {
        int c = pcnt[b * BLKROW + lane];          // BLKROW == 64 == wave
#pragma unroll
        for (int d = 32; d > 0; d >>= 1) c += __shfl_down(c, d);
        if (lane == 0) s_want = (unsigned)((3 * c > NN) ? NN : 3 * c);
    }
    for (int i = tid; i < 1024 * NC; i += K2T) h1[i] = 0;
    __syncthreads();
    const unsigned want = s_want;
    if (want == 0) { if (tid == 0) row_sumneg[b] = 0.0; return; }

    // ---- level 1: 1024-bin hist of bits[31:21] (finite >=0 -> bin <= 1019)
    const unsigned cp = lane & (NC - 1);
#pragma unroll
    for (int j = 0; j < 8; ++j) {
        atomicAdd(&h1[((kv[j].x >> 21) << 4) | cp], 1u);
        atomicAdd(&h1[((kv[j].y >> 21) << 4) | cp], 1u);
        atomicAdd(&h1[((kv[j].z >> 21) << 4) | cp], 1u);
        atomicAdd(&h1[((kv[j].w >> 21) << 4) | cp], 1u);
    }
    __syncthreads();

    // ---- level-1 scan: one bin/thread, descending suffix sums
    {
        const int bn = 1023 - tid;
        unsigned mv = 0;
#pragma unroll
        for (int c = 0; c < NC; ++c) mv += h1[(bn << 4) | c];
        unsigned v = mv;
#pragma unroll
        for (int d = 1; d < 64; d <<= 1) {
            unsigned u = __shfl_up(v, d);
            if (lane >= d) v += u;
        }
        if (lane == 63) swsum[wid] = v;
        __syncthreads();
        if (wid == 0) {
            unsigned wv = (lane < 16) ? swsum[lane] : 0;
#pragma unroll
            for (int d = 1; d < 16; d <<= 1) {
                unsigned u = __shfl_up(wv, d);
                if (lane >= d) wv += u;
            }
            if (lane < 16) swsum[lane] = wv;
        }
        __syncthreads();
        const unsigned incl = (wid ? swsum[wid - 1] : 0) + v;
        ss[bn] = incl;
        __syncthreads();
        if (incl >= want && (bn == 1023 || ss[bn + 1] < want)) {
            s_bin = bn; s_above = (bn == 1023) ? 0 : (int)ss[bn + 1];
        }
        __syncthreads();
    }
    const unsigned bsel1 = (unsigned)s_bin;
    const unsigned want1 = want - (unsigned)s_above;

    // ---- level 2: bits[20:10] of in-bin keys, straight from registers
    for (int i = tid; i < 4096; i += K2T) h1[i] = 0;
    __syncthreads();
    const unsigned c2 = lane & 1;
#pragma unroll
    for (int j = 0; j < 8; ++j) {
#define L2ADD(K) if (((K) >> 21) == bsel1) \
        atomicAdd(&h1[((((K) >> 10) & 0x7FFu) << 1) | c2], 1u);
        L2ADD(kv[j].x) L2ADD(kv[j].y) L2ADD(kv[j].z) L2ADD(kv[j].w)
#undef L2ADD
    }
    __syncthreads();
    sscan2048([&](int bn) { return h1[bn << 1] + h1[(bn << 1) | 1]; },
              ss, swsum, &s_bin, &s_above, want1, tid, lane, wid);
    const unsigned bsel2 = (unsigned)s_bin;
    const unsigned want2 = want1 - (unsigned)s_above;

    // ---- level 3: bits[9:0] (1024 live bins; upper 1024 stay zero)
    for (int i = tid; i < 4096; i += K2T) h1[i] = 0;
    __syncthreads();
    const unsigned pref = (bsel1 << 11) | bsel2;   // key bits[31:10]
#pragma unroll
    for (int j = 0; j < 8; ++j) {
#define L3ADD(K) if (((K) >> 10) == pref) \
        atomicAdd(&h1[(((K) & 0x3FFu) << 1) | c2], 1u);
        L3ADD(kv[j].x) L3ADD(kv[j].y) L3ADD(kv[j].z) L3ADD(kv[j].w)
#undef L3ADD
    }
    __syncthreads();
    sscan2048([&](int bn) { return h1[bn << 1] + h1[(bn << 1) | 1]; },
              ss, swsum, &s_bin, &s_above, want2, tid, lane, wid);
    const unsigned T = (bsel1 << 21) | (bsel2 << 10) | (unsigned)s_bin;

    // ---- final: one register pass over all 32 keys
    int above = 0;
    double sel = 0.0;
#pragma unroll
    for (int j = 0; j < 8; ++j) {
#define FIN(K) if ((K) > T) { above++; sel += (double)__uint_as_float(K); }
        FIN(kv[j].x) FIN(kv[j].y) FIN(kv[j].z) FIN(kv[j].w)
#undef FIN
    }
#pragma unroll
    for (int d = 32; d > 0; d >>= 1) {
        above += __shfl_down(above, d);
        sel   += __shfl_down(sel, d);
    }
    if (lane == 0) { swsum[wid] = (unsigned)above; sdred[wid] = sel; }
    __syncthreads();
    if (tid == 0) {
        unsigned atot = 0; double stot = 0.0;
#pragma unroll
        for (int w = 0; w < 16; ++w) { atot += swsum[w]; stot += sdred[w]; }
        const int r = (int)want - (int)atot;   // # of ==T entries selected
        row_sumneg[b] = stot + (double)r * (double)__uint_as_float(T);
    }
}

// ---------------------------------------------------------------------------
// K3: deterministic final reduction -> two scalars.
// ---------------------------------------------------------------------------
__global__ __launch_bounds__(256) void k3_final(
    const float* __restrict__ pce, const float* __restrict__ psl1,
    const int* __restrict__ pcnt, const double* __restrict__ row_sumneg,
    float* __restrict__ out)
{
    __shared__ double a[256], c[256];
    __shared__ int ic[256];
    const int tid = threadIdx.x;
    double ce = 0.0, sl = 0.0; int np = 0;
    for (int i = tid; i < K1_GRID; i += 256) {
        ce += (double)pce[i];
        sl += (double)psl1[i];
        np += pcnt[i];
    }
    a[tid] = ce; c[tid] = sl; ic[tid] = np;
    __syncthreads();
    for (int st = 128; st > 0; st >>= 1) {
        if (tid < st) {
            a[tid] += a[tid + st];
            c[tid] += c[tid + st];
            ic[tid] += ic[tid + st];
        }
        __syncthreads();
    }
    if (tid == 0) {
        double ns = 0.0;
        for (int bb = 0; bb < BB; ++bb) ns += row_sumneg[bb];
        const double npos = (double)ic[0];
        out[0] = (float)(c[0] / npos);          // smooth_l1_loss / n_pos
        out[1] = (float)((a[0] + ns) / npos);   // classification_loss / n_pos
    }
}

// ---------------------------------------------------------------------------
extern "C" void kernel_launch(void* const* d_in, const int* in_sizes, int n_in,
                              void* d_out, int out_size, void* d_ws, size_t ws_size,
                              hipStream_t stream)
{
    const float* conf   = (const float*)d_in[0];
    const float* pred   = (const float*)d_in[1];
    const int*   labels = (const int*)d_in[2];
    const float* gt     = (const float*)d_in[3];
    float* out = (float*)d_out;

    char* ws = (char*)d_ws;
    unsigned* keys       = (unsigned*)ws;                      // 4 MB
    float*    pce        = (float*)(ws + 4194304);             // 8 KB
    float*    psl1       = (float*)(ws + 4202496);             // 8 KB
    int*      pcnt       = (int*)(ws + 4210688);               // 8 KB
    double*   row_sumneg = (double*)(ws + 4218880);            // 256 B

    k1_compute<<<K1_GRID, K1_BLK, 0, stream>>>(conf, pred, labels, gt,
                                               keys, pce, psl1, pcnt);
    k2_select<<<BB, K2T, 0, stream>>>(keys, pcnt, row_sumneg);
    k3_final<<<1, 256, 0, stream>>>(pce, psl1, pcnt, row_sumneg, out);
}

// Round 11
// 37.512 us; speedup vs baseline: 1.3121x; 1.0605x over previous
//
#include <hip/hip_runtime.h>
#include <cstdint>

// Problem constants (match reference)
#define BB 32
#define NN 32768
#define CC 21
#define K1_BLK 256
#define PPT 2                                  // priors per thread
#define TILE (K1_BLK * PPT)                    // 512
#define K1_GRID ((BB * NN) / TILE)             // 2048
#define BLKROW (NN / TILE)                     // 64 k1-blocks per row

// K2 geometry
#define K2T 1024
#define NC 16                                  // level-1 hist copies

typedef float f4 __attribute__((ext_vector_type(4)));

// native transcendentals (1-ulp; output threshold 0.39 absolute -> huge slack)
__device__ __forceinline__ float fexp2(float x) {
    float r; asm("v_exp_f32 %0, %1" : "=v"(r) : "v"(x)); return r;
}
__device__ __forceinline__ float flog2(float x) {
    float r; asm("v_log_f32 %0, %1" : "=v"(r) : "v"(x)); return r;
}

// ---------------------------------------------------------------------------
// K1 v5 (R6-best, byte-identical core): register streaming, 2 priors/thread,
// all loads batched up-front. Block 0 also zeroes k2's gsum/done (k1 fully
// precedes k2 in stream order; dispatch boundary makes writes visible).
// ---------------------------------------------------------------------------
__global__ __launch_bounds__(K1_BLK) void k1_compute(
    const float* __restrict__ conf, const float* __restrict__ pred,
    const int* __restrict__ labels, const float* __restrict__ gt,
    unsigned* __restrict__ keys, float* __restrict__ pce,
    float* __restrict__ psl1, int* __restrict__ pcnt,
    double* __restrict__ gsum, unsigned* __restrict__ done)
{
    __shared__ float wce[4], wsl[4];
    __shared__ int   wcnt[4];

    const int tid = threadIdx.x;
    const int lane = tid & 63;
    const int wid = tid >> 6;
    const size_t p0 = (size_t)blockIdx.x * TILE + tid;
    const size_t p1 = p0 + K1_BLK;

    if (blockIdx.x == 0 && tid == 0) { *done = 0u; *gsum = 0.0; }

    // ---- issue ALL loads up front, nothing consumed yet
    const int lab0 = labels[p0];
    const int lab1 = labels[p1];
    const float* cp0 = conf + p0 * CC;
    const float* cp1 = conf + p1 * CC;
    f4 A0, A1, A2, A3, A4, B0, B1, B2, B3, B4;
    __builtin_memcpy(&A0, cp0 +  0, 16);
    __builtin_memcpy(&A1, cp0 +  4, 16);
    __builtin_memcpy(&A2, cp0 +  8, 16);
    __builtin_memcpy(&A3, cp0 + 12, 16);
    __builtin_memcpy(&A4, cp0 + 16, 16);
    __builtin_memcpy(&B0, cp1 +  0, 16);
    __builtin_memcpy(&B1, cp1 +  4, 16);
    __builtin_memcpy(&B2, cp1 +  8, 16);
    __builtin_memcpy(&B3, cp1 + 12, 16);
    __builtin_memcpy(&B4, cp1 + 16, 16);
    const float a20 = cp0[20];
    const float b20 = cp1[20];

    const bool pos0 = lab0 > 0;
    const bool pos1 = lab1 > 0;

    // sparse (~3%) SmoothL1 for both priors
    float sl = 0.f;
    if (pos0) {
        const float* pp = pred + p0 * 5;
        const float* gg = gt + p0 * 5;
#pragma unroll
        for (int j = 0; j < 5; ++j) {
            float d = fabsf(pp[j] - gg[j]);
            sl += (d < 1.f) ? 0.5f * d * d : (d - 0.5f);
        }
    }
    if (pos1) {
        const float* pp = pred + p1 * 5;
        const float* gg = gt + p1 * 5;
#pragma unroll
        for (int j = 0; j < 5; ++j) {
            float d = fabsf(pp[j] - gg[j]);
            sl += (d < 1.f) ? 0.5f * d * d : (d - 0.5f);
        }
    }

    // ---- prior 0: 21-class lse + logp[lab] gather via selects
    float s0 = 0.f, cl0 = 0.f;
#define KS(Q, J, IDX, LAB, SACC, CACC) { const float v_ = Q[J]; \
        SACC += fexp2(v_ * 1.44269504f); \
        CACC = ((IDX) == (LAB)) ? v_ : CACC; }
    KS(A0,0,0,lab0,s0,cl0) KS(A0,1,1,lab0,s0,cl0) KS(A0,2,2,lab0,s0,cl0) KS(A0,3,3,lab0,s0,cl0)
    KS(A1,0,4,lab0,s0,cl0) KS(A1,1,5,lab0,s0,cl0) KS(A1,2,6,lab0,s0,cl0) KS(A1,3,7,lab0,s0,cl0)
    KS(A2,0,8,lab0,s0,cl0) KS(A2,1,9,lab0,s0,cl0) KS(A2,2,10,lab0,s0,cl0) KS(A2,3,11,lab0,s0,cl0)
    KS(A3,0,12,lab0,s0,cl0) KS(A3,1,13,lab0,s0,cl0) KS(A3,2,14,lab0,s0,cl0) KS(A3,3,15,lab0,s0,cl0)
    KS(A4,0,16,lab0,s0,cl0) KS(A4,1,17,lab0,s0,cl0) KS(A4,2,18,lab0,s0,cl0) KS(A4,3,19,lab0,s0,cl0)
    { const float v_ = a20; s0 += fexp2(v_ * 1.44269504f); cl0 = (20 == lab0) ? v_ : cl0; }
    const float lse0 = 0.6931471805599453f * flog2(s0);
    const float mining0 = fmaxf(lse0 - A0[0], 0.f);
    keys[p0] = pos0 ? 0u : __float_as_uint(mining0);
    float ce = pos0 ? (lse0 - cl0) : 0.f;
    int cnt = pos0 ? 1 : 0;

    // ---- prior 1
    float s1 = 0.f, cl1 = 0.f;
    KS(B0,0,0,lab1,s1,cl1) KS(B0,1,1,lab1,s1,cl1) KS(B0,2,2,lab1,s1,cl1) KS(B0,3,3,lab1,s1,cl1)
    KS(B1,0,4,lab1,s1,cl1) KS(B1,1,5,lab1,s1,cl1) KS(B1,2,6,lab1,s1,cl1) KS(B1,3,7,lab1,s1,cl1)
    KS(B2,0,8,lab1,s1,cl1) KS(B2,1,9,lab1,s1,cl1) KS(B2,2,10,lab1,s1,cl1) KS(B2,3,11,lab1,s1,cl1)
    KS(B3,0,12,lab1,s1,cl1) KS(B3,1,13,lab1,s1,cl1) KS(B3,2,14,lab1,s1,cl1) KS(B3,3,15,lab1,s1,cl1)
    KS(B4,0,16,lab1,s1,cl1) KS(B4,1,17,lab1,s1,cl1) KS(B4,2,18,lab1,s1,cl1) KS(B4,3,19,lab1,s1,cl1)
    { const float v_ = b20; s1 += fexp2(v_ * 1.44269504f); cl1 = (20 == lab1) ? v_ : cl1; }
#undef KS
    const float lse1 = 0.6931471805599453f * flog2(s1);
    const float mining1 = fmaxf(lse1 - B0[0], 0.f);
    keys[p1] = pos1 ? 0u : __float_as_uint(mining1);
    ce += pos1 ? (lse1 - cl1) : 0.f;
    cnt += pos1 ? 1 : 0;

    // ---- deterministic block reduction (fixed trees)
#pragma unroll
    for (int d = 32; d > 0; d >>= 1) {
        ce  += __shfl_down(ce, d);
        sl  += __shfl_down(sl, d);
        cnt += __shfl_down(cnt, d);
    }
    if (lane == 0) { wce[wid] = ce; wsl[wid] = sl; wcnt[wid] = cnt; }
    __syncthreads();
    if (tid == 0) {
        float tce = 0.f, tsl = 0.f; int tc = 0;
#pragma unroll
        for (int w = 0; w < 4; ++w) { tce += wce[w]; tsl += wsl[w]; tc += wcnt[w]; }
        pce[blockIdx.x]  = tce;
        psl1[blockIdx.x] = tsl;
        pcnt[blockIdx.x] = tc;     // non-atomic per-block count
    }
}

// ---------------------------------------------------------------------------
// Suffix-scan over 2048 bins (2 bins/thread) + crossing pick.
// ---------------------------------------------------------------------------
template <class GET>
__device__ __forceinline__ void sscan2048(
    GET get, unsigned* ss, unsigned* swsum,
    int* s_bin, int* s_above, unsigned want, int tid, int lane, int wid)
{
    const int b0 = 2047 - 2 * tid;     // descending scan order
    const int b1 = 2046 - 2 * tid;
    const unsigned m0 = get(b0), m1 = get(b1);
    unsigned v = m0 + m1;
#pragma unroll
    for (int d = 1; d < 64; d <<= 1) {
        unsigned u = __shfl_up(v, d);
        if (lane >= d) v += u;
    }
    if (lane == 63) swsum[wid] = v;
    __syncthreads();
    if (wid == 0) {
        unsigned wv = (lane < 16) ? swsum[lane] : 0;
#pragma unroll
        for (int d = 1; d < 16; d <<= 1) {
            unsigned u = __shfl_up(wv, d);
            if (lane >= d) wv += u;
        }
        if (lane < 16) swsum[lane] = wv;
    }
    __syncthreads();
    const unsigned off = wid ? swsum[wid - 1] : 0;
    const unsigned incl = off + v;     // suffix through b1
    const unsigned sb0 = incl - m1;    // suffix through b0
    ss[b0] = sb0;
    ss[b1] = incl;
    __syncthreads();
    if (sb0 >= want && (b0 == 2047 || ss[b0 + 1] < want)) {
        *s_bin = b0; *s_above = (b0 == 2047) ? 0 : (int)ss[b0 + 1];
    }
    if (incl >= want && ss[b1 + 1] < want) {
        *s_bin = b1; *s_above = (int)ss[b1 + 1];
    }
    __syncthreads();
}

// ---------------------------------------------------------------------------
// K2 v8: register-resident 2-level select (level 3 replaced by in-bin mean:
// candidates share a 22-bit prefix -> relative spread < 2^-11; error
// <= want2*binwidth / n_pos ~ 1e-5, exact when ties or want2==cnt2).
// Tail: fence-free k3 fold via device-scope atomics (coherent at the
// memory-side point across XCDs); ordering by data dependency on the
// returned value. __launch_bounds__(1024,8) pins main path <=64 VGPR
// (the R7/R9 regression cause); tail doubles may spill (rare path).
// ---------------------------------------------------------------------------
__global__ __launch_bounds__(K2T, 8) void k2_select(
    const unsigned* __restrict__ keys, const int* __restrict__ pcnt,
    const float* __restrict__ pce, const float* __restrict__ psl1,
    double* __restrict__ gsum, unsigned* __restrict__ done,
    float* __restrict__ out)
{
    const int b = blockIdx.x;
    const int tid = threadIdx.x;
    const int lane = tid & 63;
    const int wid = tid >> 6;
    const unsigned* rk = keys + (size_t)b * NN;

    __shared__ unsigned h1[1024 * NC];  // 64 KB (reused for level 2)
    __shared__ unsigned ss[2048];       // 8 KB suffix sums
    __shared__ unsigned swsum[16];
    __shared__ double sdA[16], sdB[16];
    __shared__ int sdI[16];
    __shared__ int s_bin, s_above, s_last;
    __shared__ unsigned s_want;

    // ---- one coalesced read: 8 x uint4 per thread -> 32 keys in VGPRs
    uint4 kv[8];
    const uint4* rk4 = reinterpret_cast<const uint4*>(rk);
#pragma unroll
    for (int j = 0; j < 8; ++j) kv[j] = rk4[tid + j * K2T];

    // want = min(3 * row positives, NN)
    if (wid == 0) {
        int c = pcnt[b * BLKROW + lane];          // BLKROW == 64 == wave
#pragma unroll
        for (int d = 32; d > 0; d >>= 1) c += __shfl_down(c, d);
        if (lane == 0) s_want = (unsigned)((3 * c > NN) ? NN : 3 * c);
    }
    for (int i = tid; i < 1024 * NC; i += K2T) h1[i] = 0;
    __syncthreads();
    const unsigned want = s_want;

    double rowval = 0.0;    // this row's selected-negative CE sum (tid 0 only)
    if (want > 0) {
        // ---- level 1: 1024-bin hist of bits[31:21]
        const unsigned cp = lane & (NC - 1);
#pragma unroll
        for (int j = 0; j < 8; ++j) {
            atomicAdd(&h1[((kv[j].x >> 21) << 4) | cp], 1u);
            atomicAdd(&h1[((kv[j].y >> 21) << 4) | cp], 1u);
            atomicAdd(&h1[((kv[j].z >> 21) << 4) | cp], 1u);
            atomicAdd(&h1[((kv[j].w >> 21) << 4) | cp], 1u);
        }
        __syncthreads();

        // ---- level-1 scan: one bin/thread, descending suffix sums
        {
            const int bn = 1023 - tid;
            unsigned mv = 0;
#pragma unroll
            for (int c = 0; c < NC; ++c) mv += h1[(bn << 4) | c];
            unsigned v = mv;
#pragma unroll
            for (int d = 1; d < 64; d <<= 1) {
                unsigned u = __shfl_up(v, d);
                if (lane >= d) v += u;
            }
            if (lane == 63) swsum[wid] = v;
            __syncthreads();
            if (wid == 0) {
                unsigned wv = (lane < 16) ? swsum[lane] : 0;
#pragma unroll
                for (int d = 1; d < 16; d <<= 1) {
                    unsigned u = __shfl_up(wv, d);
                    if (lane >= d) wv += u;
                }
                if (lane < 16) swsum[lane] = wv;
            }
            __syncthreads();
            const unsigned incl = (wid ? swsum[wid - 1] : 0) + v;
            ss[bn] = incl;
            __syncthreads();
            if (incl >= want && (bn == 1023 || ss[bn + 1] < want)) {
                s_bin = bn; s_above = (bn == 1023) ? 0 : (int)ss[bn + 1];
            }
            __syncthreads();
        }
        const unsigned bsel1 = (unsigned)s_bin;
        const unsigned want1 = want - (unsigned)s_above;

        // ---- level 2: bits[20:10] of in-bin keys, straight from registers
        for (int i = tid; i < 4096; i += K2T) h1[i] = 0;
        __syncthreads();
        const unsigned c2 = lane & 1;
#pragma unroll
        for (int j = 0; j < 8; ++j) {
#define L2ADD(K) if (((K) >> 21) == bsel1) \
            atomicAdd(&h1[((((K) >> 10) & 0x7FFu) << 1) | c2], 1u);
            L2ADD(kv[j].x) L2ADD(kv[j].y) L2ADD(kv[j].z) L2ADD(kv[j].w)
#undef L2ADD
        }
        __syncthreads();
        sscan2048([&](int bn) { return h1[bn << 1] + h1[(bn << 1) | 1]; },
                  ss, swsum, &s_bin, &s_above, want1, tid, lane, wid);
        const unsigned bsel2 = (unsigned)s_bin;
        const unsigned want2 = want1 - (unsigned)s_above;   // 1 <= want2 <= cnt2
        const unsigned pref = (bsel1 << 11) | bsel2;        // key bits[31:10]

        // ---- final register pass: exact sum above bin + in-bin sum/count
        double aboveS = 0.0, inS = 0.0;
        int inC = 0;
#pragma unroll
        for (int j = 0; j < 8; ++j) {
#define FIN(K) { const unsigned hp = (K) >> 10; \
            if (hp > pref) aboveS += (double)__uint_as_float(K); \
            else if (hp == pref) { inS += (double)__uint_as_float(K); inC++; } }
            FIN(kv[j].x) FIN(kv[j].y) FIN(kv[j].z) FIN(kv[j].w)
#undef FIN
        }
#pragma unroll
        for (int d = 32; d > 0; d >>= 1) {
            aboveS += __shfl_down(aboveS, d);
            inS    += __shfl_down(inS, d);
            inC    += __shfl_down(inC, d);
        }
        if (lane == 0) { sdA[wid] = aboveS; sdB[wid] = inS; sdI[wid] = inC; }
        __syncthreads();
        if (tid == 0) {
            double tA = 0.0, tB = 0.0; int tC = 0;
#pragma unroll
            for (int w = 0; w < 16; ++w) { tA += sdA[w]; tB += sdB[w]; tC += sdI[w]; }
            // top-want2 of the in-bin keys ~ want2 * mean (spread < 2^-11 rel)
            rowval = tA + tB * ((double)want2 / (double)tC);
        }
    }

    // ---- fence-free completion: device-scope atomics are coherent at the
    // memory-side point across XCDs; done-add is data-dependent on the
    // gsum-add's returned value -> ordering guaranteed.
    if (tid == 0) {
        const double oldv = atomicAdd(gsum, rowval);
        unsigned inc = (__double_as_longlong(oldv) == 0x7FF7DEADBEEF0123LL)
                           ? 2u : 1u;   // always 1; unprovable -> dep kept
        const unsigned old = atomicAdd(done, inc);
        s_last = (old == BB - 1) ? 1 : 0;
    }
    __syncthreads();

    // ---- last block: global reduction of k1 partials + output write
    if (s_last) {
        double ce = 0.0, sl = 0.0; int np = 0;
        for (int i = tid; i < K1_GRID; i += K2T) {   // 2 iterations
            ce += (double)pce[i];
            sl += (double)psl1[i];
            np += pcnt[i];
        }
#pragma unroll
        for (int d = 32; d > 0; d >>= 1) {
            ce += __shfl_down(ce, d);
            sl += __shfl_down(sl, d);
            np += __shfl_down(np, d);
        }
        if (lane == 0) { sdA[wid] = ce; sdB[wid] = sl; sdI[wid] = np; }
        __syncthreads();
        if (tid == 0) {
            double tce = 0.0, tsl = 0.0; int tnp = 0;
#pragma unroll
            for (int w = 0; w < 16; ++w) { tce += sdA[w]; tsl += sdB[w]; tnp += sdI[w]; }
            const double ns = atomicAdd(gsum, 0.0);   // full sum (all 32 done)
            const double npos = (double)tnp;
            out[0] = (float)(tsl / npos);             // smooth_l1_loss / n_pos
            out[1] = (float)((tce + ns) / npos);      // classification_loss / n_pos
        }
    }
}

// ---------------------------------------------------------------------------
extern "C" void kernel_launch(void* const* d_in, const int* in_sizes, int n_in,
                              void* d_out, int out_size, void* d_ws, size_t ws_size,
                              hipStream_t stream)
{
    const float* conf   = (const float*)d_in[0];
    const float* pred   = (const float*)d_in[1];
    const int*   labels = (const int*)d_in[2];
    const float* gt     = (const float*)d_in[3];
    float* out = (float*)d_out;

    char* ws = (char*)d_ws;
    unsigned* keys = (unsigned*)ws;                  // 4 MB
    float*    pce  = (float*)(ws + 4194304);         // 8 KB
    float*    psl1 = (float*)(ws + 4202496);         // 8 KB
    int*      pcnt = (int*)(ws + 4210688);           // 8 KB
    double*   gsum = (double*)(ws + 4218880);        // 8 B
    unsigned* done = (unsigned*)(ws + 4218888);      // 4 B

    k1_compute<<<K1_GRID, K1_BLK, 0, stream>>>(conf, pred, labels, gt,
                                               keys, pce, psl1, pcnt,
                                               gsum, done);
    k2_select<<<BB, K2T, 0, stream>>>(keys, pcnt, pce, psl1,
                                      gsum, done, out);
}